// Round 6
// baseline (218.909 us; speedup 1.0000x reference)
//
#include <hip/hip_runtime.h>
#include <hip/hip_bf16.h>
#include <stdint.h>

#define NTOK 4096
#define DIN  2048
#define DOUT 2048
#define RANK 16
#define NLORA 32

typedef __attribute__((ext_vector_type(4))) float f32x4;
typedef __attribute__((ext_vector_type(8))) _Float16 f16x8;

typedef const __attribute__((address_space(1))) void* gas_ptr;
typedef __attribute__((address_space(3))) void* las_ptr;

__device__ __forceinline__ f16x8 cvt2(const float* p) {
    f32x4 a = *(const f32x4*)(p);
    f32x4 b = *(const f32x4*)(p + 4);
    f16x8 h;
    h[0] = (_Float16)a.x; h[1] = (_Float16)a.y; h[2] = (_Float16)a.z; h[3] = (_Float16)a.w;
    h[4] = (_Float16)b.x; h[5] = (_Float16)b.y; h[6] = (_Float16)b.z; h[7] = (_Float16)b.w;
    return h;
}

// ---------------------------------------------------------------------------
// K1: fused prep + LoRA. Blocks [0,1024): LoRA tile (a = b>>5, tile = b&31) —
// local ballot scan of ids, then ares = scal * x@lA^T (4-wave K-split MFMA),
// then Bresh = bias + ares@lB^T. Reads f32 inputs directly (no dependency on
// conversion blocks). Blocks [1024,3072): W -> fp16. [3072,7168): x -> fp16.
// LoRA first so its latency-bound blocks overlap the streaming converts.
// ---------------------------------------------------------------------------
__global__ __launch_bounds__(256)
void prep_lora_kernel(const float* __restrict__ x, const int* __restrict__ ids,
                      const float* __restrict__ W, const float* __restrict__ lA,
                      const float* __restrict__ lB, const float* __restrict__ bias,
                      const float* __restrict__ scal,
                      _Float16* __restrict__ xh, _Float16* __restrict__ wh,
                      _Float16* __restrict__ Bresh) {
    const int bid = blockIdx.x;
    if (bid >= 1024) {
        const int b2 = bid - 1024;
        const float* src; _Float16* dst; int lb;
        if (b2 < 2048) { src = W; dst = wh; lb = b2; }
        else           { src = x; dst = xh; lb = b2 - 2048; }
        const size_t i = ((size_t)lb * 256 + threadIdx.x) * 8;
        *(f16x8*)(dst + i) = cvt2(src + i);
        return;
    }
    // ---- LoRA tile ----
    const int a = bid >> 5, tile = bid & 31;
    const int wv = threadIdx.x >> 6, lane = threadIdx.x & 63;
    const int fr = lane & 15, fq = lane >> 4;

    __shared__ int toks[16];
    __shared__ int scnt;
    __shared__ float red[4][256];
    __shared__ _Float16 ares_h[16 * RANK];

    if (wv == 0) {
        if (lane < 16) toks[lane] = 0;          // safe dummy
        int off = 0;
        const int lo = tile * 16;
        for (int t0 = 0; t0 < NTOK; t0 += 64) {
            const bool m = (ids[t0 + lane] == a);
            unsigned long long bal = __ballot(m);
            if (m) {
                const int pos = off + __popcll(bal & ((1ULL << lane) - 1));
                if (pos >= lo && pos < lo + 16) toks[pos - lo] = t0 + lane;
            }
            off += __popcll(bal);
        }
        if (lane == 0) scnt = off;
    }
    __syncthreads();
    const int cnt = scnt;
    if (tile * 16 >= cnt) return;

    // stage 1: A-projection (K split 4 ways, 512 each)
    const int tA = toks[fr];
    const float* xr = x + (size_t)tA * DIN + wv * 512 + fq * 8;
    const float* ar = lA + (size_t)a * RANK * DIN + (size_t)fr * DIN + wv * 512 + fq * 8;
    f32x4 acc = (f32x4){0.f, 0.f, 0.f, 0.f};
#pragma unroll
    for (int st = 0; st < 16; st++) {
        f16x8 af = cvt2(xr + st * 32);
        f16x8 bf = cvt2(ar + st * 32);
        acc = __builtin_amdgcn_mfma_f32_16x16x32_f16(af, bf, acc, 0, 0, 0);
    }
#pragma unroll
    for (int j = 0; j < 4; j++) red[wv][lane * 4 + j] = acc[j];
    __syncthreads();
    if (wv == 0) {
        const float s = scal[a];
#pragma unroll
        for (int j = 0; j < 4; j++) {
            float v = red[0][lane * 4 + j] + red[1][lane * 4 + j] +
                      red[2][lane * 4 + j] + red[3][lane * 4 + j];
            ares_h[(fq * 4 + j) * RANK + fr] = (_Float16)(v * s);
        }
    }
    __syncthreads();

    // stage 2: B-expansion + bias
    f16x8 af2 = {};
    if (fq < 2) af2 = *(const f16x8*)(ares_h + fr * RANK + fq * 8);
    int tj[4];
#pragma unroll
    for (int j = 0; j < 4; j++) {
        const int idx = tile * 16 + fq * 4 + j;
        tj[j] = (idx < cnt) ? toks[fq * 4 + j] : -1;
    }
    const float* Bb = lB + (size_t)a * DOUT * RANK;
#pragma unroll 2
    for (int oi = 0; oi < 32; oi++) {
        const int o = (oi * 4 + wv) * 16 + fr;
        f16x8 bf = {};
        if (fq < 2) bf = cvt2(Bb + (size_t)o * RANK + fq * 8);
        f32x4 c = (f32x4){0.f, 0.f, 0.f, 0.f};
        c = __builtin_amdgcn_mfma_f32_16x16x32_f16(af2, bf, c, 0, 0, 0);
        const float bv = bias[o];
#pragma unroll
        for (int j = 0; j < 4; j++)
            if (tj[j] >= 0) Bresh[(size_t)tj[j] * DOUT + o] = (_Float16)(c[j] + bv);
    }
}

// ---------------------------------------------------------------------------
// K2: main GEMM fp16, m201-style phased schedule at 256x128, 8 waves (4Mx2N,
// 64x64 each), BK=64, TRIPLE-buffered LDS (144 KB, 1 block/CU, grid=256).
// 4 phases per K-tile: {ds_read subtile || 2 global_load_lds -> barrier ->
// lgkmcnt(0) -> setprio(1) 8 MFMA setprio(0) -> barrier}. vmcnt(6) once per
// K-tile (2 tiles in flight), drain only at kt==NT-2. Proven 8-slot swizzle.
// ---------------------------------------------------------------------------
#define GBK 64
#define NT (DIN / GBK)
#define BUFH 24576   // halfs per buffer: A 16384 + B 8192

__global__ __launch_bounds__(512, 1)
void gemm_kernel(const _Float16* __restrict__ Ah, const _Float16* __restrict__ Wh,
                 const _Float16* __restrict__ Bresh, float* __restrict__ out) {
    extern __shared__ _Float16 sm[];

    const int tid = threadIdx.x;
    const int wave = tid >> 6;
    const int lane = tid & 63;
    const int wr = wave >> 1, wc = wave & 1;          // 4x2 waves of 64x64

    // XCD-chunked swizzle (256 blocks, 256%8==0 -> bijective)
    const int p = blockIdx.x;
    const int L = (p & 7) * 32 + (p >> 3);
    const int bm = (L >> 4) * 256;
    const int bn = (L & 15) * 128;

    // staging: row pitch 64 halfs = 8 chunks; slot lane&7 <- chunk (lane&7)^(row&7)
    const int rsub = lane >> 3;
    const int cch = (lane & 7) ^ rsub;
    const _Float16* srcA[4];
    const _Float16* srcB[2];
#pragma unroll
    for (int i = 0; i < 4; i++) {
        const int row = (wave * 4 + i) * 8 + rsub;    // 256 rows of A
        srcA[i] = Ah + (size_t)(bm + row) * DIN + cch * 8;
    }
#pragma unroll
    for (int i = 0; i < 2; i++) {
        const int row = (wave * 2 + i) * 8 + rsub;    // 128 rows of B
        srcB[i] = Wh + (size_t)(bn + row) * DIN + cch * 8;
    }

    const int fr = lane & 15;
    const int fq = lane >> 4;

    f32x4 acc[4][4];
#pragma unroll
    for (int i = 0; i < 4; i++)
#pragma unroll
        for (int j = 0; j < 4; j++) acc[i][j] = (f32x4){0.f, 0.f, 0.f, 0.f};

#define GLDS(srcp, dstp) __builtin_amdgcn_global_load_lds((gas_ptr)(srcp), (las_ptr)(dstp), 16, 0, 0)
#define STAGE_ALL(buf, koff)                                                           \
    do {                                                                               \
        _Pragma("unroll")                                                              \
        for (int i = 0; i < 4; i++)                                                    \
            GLDS(srcA[i] + (koff), sm + (buf) * BUFH + (wave * 4 + i) * 512);          \
        _Pragma("unroll")                                                              \
        for (int i = 0; i < 2; i++)                                                    \
            GLDS(srcB[i] + (koff), sm + (buf) * BUFH + 16384 + (wave * 2 + i) * 512);  \
    } while (0)

    STAGE_ALL(0, 0);
    STAGE_ALL(1, GBK);
    asm volatile("s_waitcnt vmcnt(6)" ::: "memory");   // tile 0 landed
    __builtin_amdgcn_s_barrier();

    for (int kt = 0; kt < NT; ++kt) {
        const _Float16* Ab = sm + (kt % 3) * BUFH;
        const _Float16* Bb = Ab + 16384;
        _Float16* Asn = sm + ((kt + 2) % 3) * BUFH;
        _Float16* Bsn = Asn + 16384;
        const int kn = (kt + 2) * GBK;
        const bool doStage = (kt < NT - 2);

#pragma unroll
        for (int kk = 0; kk < 2; kk++) {
            f16x8 av[4], bv[4];
            // ---- phase A: read av[0..3], bv[0..1]; stage 2 loads ----
#pragma unroll
            for (int mi = 0; mi < 4; mi++) {
                const int row = wr * 64 + mi * 16 + fr;
                av[mi] = *(const f16x8*)(Ab + row * 64 + (((kk * 4 + fq) ^ (row & 7)) * 8));
            }
#pragma unroll
            for (int ni = 0; ni < 2; ni++) {
                const int row = wc * 64 + ni * 16 + fr;
                bv[ni] = *(const f16x8*)(Bb + row * 64 + (((kk * 4 + fq) ^ (row & 7)) * 8));
            }
            if (doStage) {
                if (kk == 0) {
                    GLDS(srcA[0] + kn, Asn + (wave * 4 + 0) * 512);
                    GLDS(srcA[1] + kn, Asn + (wave * 4 + 1) * 512);
                } else {
                    GLDS(srcB[0] + kn, Bsn + (wave * 2 + 0) * 512);
                    GLDS(srcB[1] + kn, Bsn + (wave * 2 + 1) * 512);
                }
            }
            __builtin_amdgcn_s_barrier();
            asm volatile("s_waitcnt lgkmcnt(0)" ::: "memory");
            __builtin_amdgcn_sched_barrier(0);
            __builtin_amdgcn_s_setprio(1);
#pragma unroll
            for (int mi = 0; mi < 4; mi++)
#pragma unroll
                for (int ni = 0; ni < 2; ni++)
                    acc[mi][ni] = __builtin_amdgcn_mfma_f32_16x16x32_f16(av[mi], bv[ni], acc[mi][ni], 0, 0, 0);
            __builtin_amdgcn_s_setprio(0);
            __builtin_amdgcn_s_barrier();

            // ---- phase B: read bv[2..3]; stage 2 loads; tile-end vmcnt ----
#pragma unroll
            for (int ni = 2; ni < 4; ni++) {
                const int row = wc * 64 + ni * 16 + fr;
                bv[ni] = *(const f16x8*)(Bb + row * 64 + (((kk * 4 + fq) ^ (row & 7)) * 8));
            }
            if (doStage && kk == 0) {
                GLDS(srcA[2] + kn, Asn + (wave * 4 + 2) * 512);
                GLDS(srcA[3] + kn, Asn + (wave * 4 + 3) * 512);
            }
            if (kk == 1) {
                if (kt < NT - 2)       asm volatile("s_waitcnt vmcnt(6)" ::: "memory");
                else if (kt == NT - 2) asm volatile("s_waitcnt vmcnt(0)" ::: "memory");
            }
            __builtin_amdgcn_s_barrier();
            asm volatile("s_waitcnt lgkmcnt(0)" ::: "memory");
            __builtin_amdgcn_sched_barrier(0);
            __builtin_amdgcn_s_setprio(1);
#pragma unroll
            for (int mi = 0; mi < 4; mi++)
#pragma unroll
                for (int ni = 2; ni < 4; ni++)
                    acc[mi][ni] = __builtin_amdgcn_mfma_f32_16x16x32_f16(av[mi], bv[ni], acc[mi][ni], 0, 0, 0);
            __builtin_amdgcn_s_setprio(0);
            __builtin_amdgcn_s_barrier();
        }
    }

    // epilogue: out = acc + Bresh
#pragma unroll
    for (int mi = 0; mi < 4; mi++) {
#pragma unroll
        for (int j = 0; j < 4; j++) {
            const int n = bm + wr * 64 + mi * 16 + fq * 4 + j;
#pragma unroll
            for (int ni = 0; ni < 4; ni++) {
                const int o = bn + wc * 64 + ni * 16 + fr;
                out[(size_t)n * DOUT + o] = acc[mi][ni][j] + (float)Bresh[(size_t)n * DOUT + o];
            }
        }
    }
}

extern "C" void kernel_launch(void* const* d_in, const int* in_sizes, int n_in,
                              void* d_out, int out_size, void* d_ws, size_t ws_size,
                              hipStream_t stream) {
    const float* x    = (const float*)d_in[0];
    const int*   ids  = (const int*)d_in[1];
    const float* W    = (const float*)d_in[2];
    const float* bias = (const float*)d_in[3];
    const float* lA   = (const float*)d_in[4];
    const float* lB   = (const float*)d_in[5];
    const float* scal = (const float*)d_in[6];
    float* out = (float*)d_out;

    _Float16* xh    = (_Float16*)d_ws;                    // 16 MB
    _Float16* wh    = xh + (size_t)NTOK * DIN;            // 8 MB
    _Float16* Bresh = wh + (size_t)DOUT * DIN;            // 16 MB

    prep_lora_kernel<<<dim3(7168), 256, 0, stream>>>(
        x, ids, W, lA, lB, bias, scal, xh, wh, Bresh);
    gemm_kernel<<<dim3(256), 512, 144 * 1024, stream>>>(
        xh, wh, Bresh, out);
}

// Round 7
// 165.596 us; speedup vs baseline: 1.3219x; 1.3219x over previous
//
#include <hip/hip_runtime.h>
#include <hip/hip_bf16.h>
#include <stdint.h>

#define NTOK 4096
#define DIN  2048
#define DOUT 2048
#define RANK 16
#define NLORA 32
#define LCAP 512

typedef __attribute__((ext_vector_type(4))) float f32x4;
typedef __attribute__((ext_vector_type(8))) _Float16 f16x8;
typedef __attribute__((ext_vector_type(4))) _Float16 f16x4;

typedef const __attribute__((address_space(1))) void* gas_ptr;
typedef __attribute__((address_space(3))) void* las_ptr;

__device__ __forceinline__ f16x8 cvt8(const float* p) {
    f32x4 a = *(const f32x4*)(p);
    f32x4 b = *(const f32x4*)(p + 4);
    f16x8 h;
    h[0] = (_Float16)a.x; h[1] = (_Float16)a.y; h[2] = (_Float16)a.z; h[3] = (_Float16)a.w;
    h[4] = (_Float16)b.x; h[5] = (_Float16)b.y; h[6] = (_Float16)b.z; h[7] = (_Float16)b.w;
    return h;
}

// ---------------------------------------------------------------------------
// K1: converts (16 elems/thread): W [0,1024), x [1024,3072), lA [3072,3328),
// lB [3328,3584); token lists [3584,3616) (round-3-validated ballot scan).
// ---------------------------------------------------------------------------
__global__ __launch_bounds__(256)
void prep_kernel(const float* __restrict__ x, const int* __restrict__ ids,
                 const float* __restrict__ W, const float* __restrict__ lA,
                 const float* __restrict__ lB,
                 _Float16* __restrict__ xh, _Float16* __restrict__ wh,
                 _Float16* __restrict__ lAh, _Float16* __restrict__ lBh,
                 int* __restrict__ list, int* __restrict__ counts) {
    const int bid = blockIdx.x;
    if (bid < 3584) {
        const float* src; _Float16* dst; int lb;
        if      (bid < 1024) { src = W;  dst = wh;  lb = bid; }
        else if (bid < 3072) { src = x;  dst = xh;  lb = bid - 1024; }
        else if (bid < 3328) { src = lA; dst = lAh; lb = bid - 3072; }
        else                 { src = lB; dst = lBh; lb = bid - 3328; }
        const size_t i = ((size_t)lb * 256 + threadIdx.x) * 16;
        *(f16x8*)(dst + i)     = cvt8(src + i);
        *(f16x8*)(dst + i + 8) = cvt8(src + i + 8);
        return;
    }
    const int a = bid - 3584;
    const int wv = threadIdx.x >> 6;
    const int lane = threadIdx.x & 63;
    __shared__ int wcnt[4];
    int c = 0;
    for (int t0 = wv * 1024; t0 < wv * 1024 + 1024; t0 += 64)
        c += __popcll(__ballot(ids[t0 + lane] == a));
    if (lane == 0) wcnt[wv] = c;
    __syncthreads();
    int off = 0;
    for (int w = 0; w < wv; w++) off += wcnt[w];
    if (threadIdx.x == 0) counts[a] = wcnt[0] + wcnt[1] + wcnt[2] + wcnt[3];
    for (int t0 = wv * 1024; t0 < wv * 1024 + 1024; t0 += 64) {
        const int t = t0 + lane;
        const bool m = (ids[t] == a);
        unsigned long long bal = __ballot(m);
        if (m) {
            int pos = off + __popcll(bal & ((1ULL << lane) - 1));
            if (pos < LCAP) list[a * LCAP + pos] = t;
        }
        off += __popcll(bal);
    }
}

// ---------------------------------------------------------------------------
// K2: fused LoRA A+B per (adapter, 16-token tile).
//   stage 1 (round-5-validated): ares = scal * x @ lA^T, 8-wave K-split MFMA
//            + cross-wave LDS reduce, kept in LDS fp16.
//   stage 2 (NEW operand order): C = mfma(lB_frag, ares_frag) -> C[o][token];
//            lane (fr,fq) holds 4 CONSECUTIVE o for token fr -> 8B vector
//            stores of Bresh (was scalar 2B scattered).
// ---------------------------------------------------------------------------
__global__ __launch_bounds__(512)
void lora_kernel(const _Float16* __restrict__ xh, const _Float16* __restrict__ lAh,
                 const _Float16* __restrict__ lBh, const float* __restrict__ bias,
                 const float* __restrict__ scal, const int* __restrict__ list,
                 const int* __restrict__ counts, _Float16* __restrict__ Bresh) {
    const int a = blockIdx.x, tile = blockIdx.y;
    const int cnt = counts[a];
    if (tile * 16 >= cnt) return;
    const int wave = threadIdx.x >> 6;
    const int lane = threadIdx.x & 63;
    const int fr = lane & 15, fq = lane >> 4;

    __shared__ float red[8][256];
    __shared__ _Float16 ares_h[16 * RANK];

    const int idxA = tile * 16 + fr;
    const int tA = (idxA < cnt) ? list[a * LCAP + idxA] : list[a * LCAP];

    // ---- stage 1: A-projection ----
    const _Float16* xr = xh + (size_t)tA * DIN + wave * 256 + fq * 8;
    const _Float16* ar = lAh + (size_t)a * RANK * DIN + (size_t)fr * DIN + wave * 256 + fq * 8;
    f32x4 acc = (f32x4){0.f, 0.f, 0.f, 0.f};
#pragma unroll
    for (int st = 0; st < 8; st++) {
        f16x8 af = *(const f16x8*)(xr + st * 32);
        f16x8 bf = *(const f16x8*)(ar + st * 32);
        acc = __builtin_amdgcn_mfma_f32_16x16x32_f16(af, bf, acc, 0, 0, 0);
    }
#pragma unroll
    for (int j = 0; j < 4; j++) red[wave][lane * 4 + j] = acc[j];
    __syncthreads();
    if (wave == 0) {
        const float s = scal[a];
#pragma unroll
        for (int j = 0; j < 4; j++) {
            float v = 0.f;
#pragma unroll
            for (int w = 0; w < 8; w++) v += red[w][lane * 4 + j];
            ares_h[(fq * 4 + j) * RANK + fr] = (_Float16)(v * s);   // [token][rank]
        }
    }
    __syncthreads();

    // ---- stage 2: B-expansion + bias, swapped operands ----
    // B-operand (col = token fr): ares_h[fr][fq*8..+8], zero-pad k>=16
    f16x8 ares_frag = {};
    if (fq < 2) ares_frag = *(const f16x8*)(ares_h + fr * RANK + fq * 8);
    const bool valid = (tile * 16 + fr < cnt);
    const int tok = tA;                       // token this lane stores rows for
    const _Float16* Bb = lBh + (size_t)a * DOUT * RANK;
    _Float16* outrow = Bresh + (size_t)tok * DOUT;

#pragma unroll 4
    for (int oi = 0; oi < 16; oi++) {
        const int ot = wave * 16 + oi;        // o-tile 0..127
        // A-operand (row = o): lB[(ot*16+fr)][fq*8..+8], zero-pad k>=16
        f16x8 bfrag = {};
        if (fq < 2) bfrag = *(const f16x8*)(Bb + (size_t)(ot * 16 + fr) * RANK + fq * 8);
        f32x4 c = (f32x4){0.f, 0.f, 0.f, 0.f};
        c = __builtin_amdgcn_mfma_f32_16x16x32_f16(bfrag, ares_frag, c, 0, 0, 0);
        // C[row = o = ot*16 + fq*4 + j][col = token fr]
        const f32x4 bv = *(const f32x4*)(bias + ot * 16 + fq * 4);
        if (valid) {
            f16x4 o4;
            o4[0] = (_Float16)(c[0] + bv.x);
            o4[1] = (_Float16)(c[1] + bv.y);
            o4[2] = (_Float16)(c[2] + bv.z);
            o4[3] = (_Float16)(c[3] + bv.w);
            *(f16x4*)(outrow + ot * 16 + fq * 4) = o4;
        }
    }
}

// ---------------------------------------------------------------------------
// K3: main GEMM fp16 — EXACT round-5 kernel (43.6 us, MfmaUtil 32.5%,
// conflicts 0). 128x128, 4 waves, BK=64, 64 KB dbuf, counted vmcnt(8),
// 8-slot swizzle, XCD-chunked block swizzle.
// ---------------------------------------------------------------------------
#define GBK 64
#define NT (DIN / GBK)

__global__ __launch_bounds__(256, 2)
void gemm_kernel(const _Float16* __restrict__ Ah, const _Float16* __restrict__ Wh,
                 const _Float16* __restrict__ Bresh, float* __restrict__ out) {
    extern __shared__ _Float16 sm[];
    _Float16* As = sm;             // 2 x 8192 halfs
    _Float16* Bs = sm + 16384;     // 2 x 8192 halfs

    const int tid = threadIdx.x;
    const int wave = tid >> 6;
    const int lane = tid & 63;
    const int wr = wave >> 1, wc = wave & 1;

    const int p = blockIdx.x;
    const int L = (p & 7) * 64 + (p >> 3);
    const int bm = (L >> 4) * 128;
    const int bn = (L & 15) * 128;

    const int rsub = lane >> 3;
    const int cch = (lane & 7) ^ rsub;
    const _Float16* srcA[4];
    const _Float16* srcB[4];
#pragma unroll
    for (int i = 0; i < 4; i++) {
        const int row = (wave * 4 + i) * 8 + rsub;
        srcA[i] = Ah + (size_t)(bm + row) * DIN + cch * 8;
        srcB[i] = Wh + (size_t)(bn + row) * DIN + cch * 8;
    }

    const int fr = lane & 15;
    const int fq = lane >> 4;

    f32x4 acc[4][4];
#pragma unroll
    for (int i = 0; i < 4; i++)
#pragma unroll
        for (int j = 0; j < 4; j++) acc[i][j] = (f32x4){0.f, 0.f, 0.f, 0.f};

#define STAGE(buf, koff)                                                                  \
    do {                                                                                  \
        _Pragma("unroll")                                                                 \
        for (int i = 0; i < 4; i++) {                                                     \
            __builtin_amdgcn_global_load_lds((gas_ptr)(srcA[i] + (koff)),                 \
                (las_ptr)(As + (buf) * 8192 + (wave * 4 + i) * 512), 16, 0, 0);           \
            __builtin_amdgcn_global_load_lds((gas_ptr)(srcB[i] + (koff)),                 \
                (las_ptr)(Bs + (buf) * 8192 + (wave * 4 + i) * 512), 16, 0, 0);           \
        }                                                                                 \
    } while (0)

    STAGE(0, 0);

    for (int kt = 0; kt < NT; ++kt) {
        const int cur = kt & 1;
        if (kt < NT - 1) {
            STAGE(cur ^ 1, (kt + 1) * GBK);
            asm volatile("s_waitcnt vmcnt(8)" ::: "memory");
        } else {
            asm volatile("s_waitcnt vmcnt(0)" ::: "memory");
        }
        __builtin_amdgcn_s_barrier();
        __builtin_amdgcn_sched_barrier(0);

        const _Float16* Ab = As + cur * 8192;
        const _Float16* Bb = Bs + cur * 8192;
#pragma unroll
        for (int kk = 0; kk < 2; kk++) {
            f16x8 av[4], bv[4];
#pragma unroll
            for (int mi = 0; mi < 4; mi++) {
                const int row = wr * 64 + mi * 16 + fr;
                const int slot = (kk * 4 + fq) ^ (row & 7);
                av[mi] = *(const f16x8*)(Ab + row * 64 + slot * 8);
            }
#pragma unroll
            for (int ni = 0; ni < 4; ni++) {
                const int row = wc * 64 + ni * 16 + fr;
                const int slot = (kk * 4 + fq) ^ (row & 7);
                bv[ni] = *(const f16x8*)(Bb + row * 64 + slot * 8);
            }
            __builtin_amdgcn_s_setprio(1);
#pragma unroll
            for (int mi = 0; mi < 4; mi++)
#pragma unroll
                for (int ni = 0; ni < 4; ni++)
                    acc[mi][ni] = __builtin_amdgcn_mfma_f32_16x16x32_f16(av[mi], bv[ni], acc[mi][ni], 0, 0, 0);
            __builtin_amdgcn_s_setprio(0);
        }
        __builtin_amdgcn_s_barrier();
    }

#pragma unroll
    for (int mi = 0; mi < 4; mi++) {
#pragma unroll
        for (int j = 0; j < 4; j++) {
            const int n = bm + wr * 64 + mi * 16 + fq * 4 + j;
#pragma unroll
            for (int ni = 0; ni < 4; ni++) {
                const int o = bn + wc * 64 + ni * 16 + fr;
                out[(size_t)n * DOUT + o] = acc[mi][ni][j] + (float)Bresh[(size_t)n * DOUT + o];
            }
        }
    }
}

extern "C" void kernel_launch(void* const* d_in, const int* in_sizes, int n_in,
                              void* d_out, int out_size, void* d_ws, size_t ws_size,
                              hipStream_t stream) {
    const float* x    = (const float*)d_in[0];
    const int*   ids  = (const int*)d_in[1];
    const float* W    = (const float*)d_in[2];
    const float* bias = (const float*)d_in[3];
    const float* lA   = (const float*)d_in[4];
    const float* lB   = (const float*)d_in[5];
    const float* scal = (const float*)d_in[6];
    float* out = (float*)d_out;

    _Float16* xh    = (_Float16*)d_ws;                       // 16.8 MB
    _Float16* wh    = xh + (size_t)NTOK * DIN;               //  8.4 MB
    _Float16* lAh   = wh + (size_t)DOUT * DIN;               //  2.1 MB
    _Float16* lBh   = lAh + (size_t)NLORA * RANK * DIN;      //  2.1 MB
    _Float16* Bresh = lBh + (size_t)NLORA * DOUT * RANK;     // 16.8 MB
    int* list   = (int*)(Bresh + (size_t)NTOK * DOUT);
    int* counts = list + (size_t)NLORA * LCAP;

    prep_kernel<<<dim3(3584 + NLORA), 256, 0, stream>>>(
        x, ids, W, lA, lB, xh, wh, lAh, lBh, list, counts);
    lora_kernel<<<dim3(NLORA, 32), 512, 0, stream>>>(
        xh, lAh, lBh, bias, scal, list, counts, Bresh);
    gemm_kernel<<<dim3(512), 256, 64 * 1024, stream>>>(
        xh, wh, Bresh, out);
}